// Round 1
// baseline (2076.224 us; speedup 1.0000x reference)
//
#include <hip/hip_runtime.h>
#include <math.h>

#define B_ 4
#define N_ 65536
#define C_ 192

// ---------------- workspace layout (floats) ----------------
// wkv   [384][192]      @ 0        (packed k,v rows of qkv_w: c-major)
// bkv   [384]           @ 73728
// kv    [4][6][32][32]  @ 74112    (zeroed each call, atomically accumulated)
// Pt    [4][192][192]   @ 98688    (Pt[b][cp][c])
// c0    [4][192]        @ 246144
// M1t   [4][192][192]   @ 246912   (M1t[b][j][c])
// d1    [4][192]        @ 394368
// total 395136 floats = 1.58 MB

// ---------------- kernel 0: pack k/v weight rows ----------------
__global__ void k0_pack(const float* __restrict__ qkv_w,
                        const float* __restrict__ qkv_b,
                        float* __restrict__ wkv, float* __restrict__ bkv)
{
    int t = threadIdx.x;
    if (blockIdx.x < 288) {
        int idx = blockIdx.x * 256 + t;           // < 73728
        int r = idx / 192, c = idx % 192;
        int h = r >> 6, r2 = r & 63;              // r2<32 -> k row, else v row
        wkv[idx] = qkv_w[(h * 96 + 32 + r2) * 192 + c];
    } else if (t < 384) {
        int h = t >> 6, r2 = t & 63;
        bkv[t] = qkv_b[h * 96 + 32 + r2];
    }
}

// ---------------- kernel 1: k/v projection + LN + kv reduction ----------------
// grid (256, 4), block 256. Each block: 8 tiles of 32 pixels.
__global__ __launch_bounds__(256, 2)
void k1_kv(const float* __restrict__ x, const float* __restrict__ wkv,
           const float* __restrict__ bkv,
           const float* __restrict__ klnw, const float* __restrict__ klnb,
           const float* __restrict__ vlnw, const float* __restrict__ vlnb,
           float* __restrict__ kvg)
{
    __shared__ __align__(16) float lds[12544];
    float4* xs4   = (float4*)lds;               // [32][50] float4  (x tile)
    float*  kvtile = lds;                       // [32][388] (aliases xs+wch)
    float4* wch4  = (float4*)(lds + 6400);      // [2][384*2] dbuf weight chunk
    const float4* wkv4 = (const float4*)wkv;

    const int t  = threadIdx.x;
    const int b  = blockIdx.y;
    const int pg = t & 7;            // pixels pg + 8*pi
    const int cg = t >> 3;           // channels cg + 32*j, j<12

    const int oh  = t >> 5;          // t<192: head (also LN head)
    const int orr = t & 31;          // LN: pixel; outer: (dq,eo)
    const int odq = orr >> 2;        // d-quad 0..7
    const int oeo = orr & 3;         // e-oct 0..3

    float kvacc[4][8];
#pragma unroll
    for (int a = 0; a < 4; ++a)
#pragma unroll
        for (int e = 0; e < 8; ++e) kvacc[a][e] = 0.f;

    float bias[12];
#pragma unroll
    for (int j = 0; j < 12; ++j) bias[j] = bkv[cg + 32*j];

    for (int it = 0; it < 8; ++it) {
        int tile = blockIdx.x * 8 + it;
        const float4* xg4 = (const float4*)(x + ((long)b * N_ + (long)tile * 32) * C_);

        // stage x tile (32x192) + weight chunk 0
#pragma unroll
        for (int i = 0; i < 6; ++i) {
            int lin = t + 256*i;                 // < 1536
            xs4[(lin/48)*50 + (lin%48)] = xg4[lin];
        }
#pragma unroll
        for (int i = 0; i < 3; ++i) {
            int lin = t + 256*i;                 // < 768
            int row = lin >> 1, q = lin & 1;
            wch4[row*2 + q] = wkv4[row*48 + q];
        }
        float acc[4][12];
#pragma unroll
        for (int j = 0; j < 12; ++j)
#pragma unroll
            for (int pi = 0; pi < 4; ++pi) acc[pi][j] = bias[j];
        __syncthreads();

        // GEMM: 24 chunks of K=8, double-buffered weights
        for (int ck = 0; ck < 24; ++ck) {
            int cb = ck & 1;
            if (ck < 23) {
                int nb = cb ^ 1;
                int k04 = (ck + 1) * 2;
#pragma unroll
                for (int i = 0; i < 3; ++i) {
                    int lin = t + 256*i;
                    int row = lin >> 1, q = lin & 1;
                    wch4[nb*768 + row*2 + q] = wkv4[row*48 + k04 + q];
                }
            }
#pragma unroll
            for (int q2 = 0; q2 < 2; ++q2) {
                float4 xv[4];
#pragma unroll
                for (int pi = 0; pi < 4; ++pi)
                    xv[pi] = xs4[(pg + 8*pi)*50 + ck*2 + q2];
#pragma unroll
                for (int j = 0; j < 12; ++j) {
                    float4 wv = wch4[cb*768 + (cg + 32*j)*2 + q2];
#pragma unroll
                    for (int pi = 0; pi < 4; ++pi)
                        acc[pi][j] += xv[pi].x*wv.x + xv[pi].y*wv.y
                                    + xv[pi].z*wv.z + xv[pi].w*wv.w;
                }
            }
            __syncthreads();
        }

        // scatter result to kvtile[32][388] (overwrites xs/wch)
#pragma unroll
        for (int j = 0; j < 12; ++j) {
            int c = cg + 32*j;
#pragma unroll
            for (int pi = 0; pi < 4; ++pi)
                kvtile[(pg + 8*pi)*388 + c] = acc[pi][j];
        }
        __syncthreads();

        // LayerNorm per (pixel=orr, head=oh): unbiased std, /(std+eps)
        if (t < 192) {
            float* row = kvtile + orr * 388 + oh * 64;
            float sk=0.f, skk=0.f, sv=0.f, svv=0.f;
#pragma unroll
            for (int d = 0; d < 32; ++d) { float u = row[d];    sk += u; skk += u*u; }
#pragma unroll
            for (int d = 0; d < 32; ++d) { float u = row[32+d]; sv += u; svv += u*u; }
            float mk = sk * (1.f/32.f), mv = sv * (1.f/32.f);
            float vark = fmaxf((skk - 32.f*mk*mk) * (1.f/31.f), 0.f);
            float varv = fmaxf((svv - 32.f*mv*mv) * (1.f/31.f), 0.f);
            float ik = 1.f / (sqrtf(vark) + 1e-5f);
            float iv = 1.f / (sqrtf(varv) + 1e-5f);
            const float* kw = klnw + oh*32; const float* kb = klnb + oh*32;
            const float* vw = vlnw + oh*32; const float* vb = vlnb + oh*32;
#pragma unroll
            for (int d = 0; d < 32; ++d)
                row[d] = kw[d] * ((row[d] - mk) * ik) + kb[d];
#pragma unroll
            for (int d = 0; d < 32; ++d)
                row[32+d] = vw[d] * ((row[32+d] - mv) * iv) + vb[d];
        }
        __syncthreads();

        // outer-product accumulate: thread owns (head oh, d-quad odq, e-oct oeo)
        if (t < 192) {
            const float4* kt4 = (const float4*)kvtile;
#pragma unroll 4
            for (int p = 0; p < 32; ++p) {
                int base4 = p*97 + oh*16;        // 388/4 = 97
                float4 kq = kt4[base4 + odq];
                float4 v1 = kt4[base4 + 8 + oeo*2];
                float4 v2 = kt4[base4 + 9 + oeo*2];
                float kd[4] = {kq.x, kq.y, kq.z, kq.w};
                float ve[8] = {v1.x,v1.y,v1.z,v1.w, v2.x,v2.y,v2.z,v2.w};
#pragma unroll
                for (int di = 0; di < 4; ++di)
#pragma unroll
                    for (int ej = 0; ej < 8; ++ej)
                        kvacc[di][ej] += kd[di] * ve[ej];
            }
        }
        __syncthreads();
    }

    if (t < 192) {
        float* dst = kvg + (((long)b*6 + oh)*32 + odq*4)*32 + oeo*8;
        const float sc = 1.f / (float)N_;
#pragma unroll
        for (int di = 0; di < 4; ++di)
#pragma unroll
            for (int ej = 0; ej < 8; ++ej)
                atomicAdd(dst + di*32 + ej, kvacc[di][ej] * sc);
    }
}

// ---------------- kernel 2a: Pt[b][cp][c], c0[b][cp] ----------------
__global__ void k2a(const float* __restrict__ qkv_w, const float* __restrict__ qkv_b,
                    const float* __restrict__ kvg,
                    float* __restrict__ Pt, float* __restrict__ c0)
{
    int b = blockIdx.y;
    const float* kvb = kvg + (long)b * 6144;
    if (blockIdx.x < 144) {
        int idx = blockIdx.x * 256 + threadIdx.x;   // < 36864
        int c = idx % 192, cp = idx / 192;
        int h = cp >> 5, e = cp & 31;
        float s = 0.f;
#pragma unroll 8
        for (int d = 0; d < 32; ++d)
            s += qkv_w[(h*96 + d)*192 + c] * kvb[(h*32 + d)*32 + e];
        Pt[(long)b*36864 + cp*192 + c] = s;
    } else if (threadIdx.x < 192) {
        int cp = threadIdx.x, h = cp >> 5, e = cp & 31;
        float s = 0.f;
#pragma unroll 8
        for (int d = 0; d < 32; ++d)
            s += qkv_b[h*96 + d] * kvb[(h*32 + d)*32 + e];
        c0[b*192 + cp] = s;
    }
}

// ---------------- kernel 2b: M1t[b][j][c], d1[b][j] ----------------
__global__ void k2b(const float* __restrict__ o1w, const float* __restrict__ o1b,
                    const float* __restrict__ Pt, const float* __restrict__ c0,
                    float* __restrict__ M1t, float* __restrict__ d1)
{
    int b = blockIdx.y;
    if (blockIdx.x < 144) {
        int idx = blockIdx.x * 256 + threadIdx.x;   // < 36864
        int c = idx % 192, j = idx / 192;
        float s = o1w[j*192 + c];                   // identity (residual) term
        const float* pb = Pt + (long)b*36864;
        const float* wr = o1w + j*192;
#pragma unroll 8
        for (int cp = 0; cp < 192; ++cp)
            s += pb[cp*192 + c] * wr[cp];
        M1t[(long)b*36864 + j*192 + c] = s;
    } else if (threadIdx.x < 192) {
        int j = threadIdx.x;
        float s = o1b[j];
        const float* wr = o1w + j*192;
#pragma unroll 8
        for (int cp = 0; cp < 192; ++cp)
            s += c0[b*192 + cp] * wr[cp];
        d1[b*192 + j] = s;
    }
}

// ---------------- kernel 3: out = gelu(x@M1t^T + d1)@o2w^T + o2b + x ----------------
// grid (256, 4), block 256. Tiles of 32 pixels; io buffer holds x -> h -> out.
__global__ __launch_bounds__(256, 2)
void k3_out(const float* __restrict__ x, const float* __restrict__ M1t,
            const float* __restrict__ d1, const float* __restrict__ o2w,
            const float* __restrict__ o2b, float* __restrict__ out)
{
    __shared__ __align__(16) float lds[12544];
    float4* io4  = (float4*)lds;                 // [32][50] float4
    float*  io   = lds;
    float4* wch4 = (float4*)(lds + 6400);        // [2][4 planes][192] float4
    const int t  = threadIdx.x;
    const int b  = blockIdx.y;
    const int pg = t & 7;                        // pixels pg + 8*pi
    const int jg = t >> 3;                       // out channels jg + 32*jj, jj<6
    const float4* W14 = (const float4*)(M1t + (long)b * 36864);
    const float4* W24 = (const float4*)o2w;

    float dinit[6], binit[6];
#pragma unroll
    for (int jj = 0; jj < 6; ++jj) {
        dinit[jj] = d1[b*192 + jg + 32*jj];
        binit[jj] = o2b[jg + 32*jj];
    }

    for (int it = 0; it < 8; ++it) {
        int tile = blockIdx.x * 8 + it;
        long base = ((long)b * N_ + (long)tile * 32) * C_;
        const float4* xg4 = (const float4*)(x + base);

#pragma unroll
        for (int i = 0; i < 6; ++i) {
            int lin = t + 256*i;
            io4[(lin/48)*50 + (lin%48)] = xg4[lin];
        }
        // stage GEMM1 chunk 0: planes [q2][j]
#pragma unroll
        for (int i = 0; i < 3; ++i) {
            int lin = t + 256*i;                 // < 768
            int j = lin >> 2, q2 = lin & 3;
            wch4[q2*192 + j] = W14[j*48 + q2];
        }
        float acc[4][6];
#pragma unroll
        for (int jj = 0; jj < 6; ++jj)
#pragma unroll
            for (int pi = 0; pi < 4; ++pi) acc[pi][jj] = dinit[jj];
        __syncthreads();

        // GEMM1: 12 chunks of K=16 over c
        for (int ck = 0; ck < 12; ++ck) {
            int cb = ck & 1;
            if (ck < 11) {
                int nb = cb ^ 1;
#pragma unroll
                for (int i = 0; i < 3; ++i) {
                    int lin = t + 256*i;
                    int j = lin >> 2, q2 = lin & 3;
                    wch4[nb*768 + q2*192 + j] = W14[j*48 + (ck+1)*4 + q2];
                }
            }
#pragma unroll
            for (int q2 = 0; q2 < 4; ++q2) {
                float4 xv[4];
#pragma unroll
                for (int pi = 0; pi < 4; ++pi)
                    xv[pi] = io4[(pg + 8*pi)*50 + ck*4 + q2];
#pragma unroll
                for (int jj = 0; jj < 6; ++jj) {
                    float4 wv = wch4[cb*768 + q2*192 + jg + 32*jj];
#pragma unroll
                    for (int pi = 0; pi < 4; ++pi)
                        acc[pi][jj] += xv[pi].x*wv.x + xv[pi].y*wv.y
                                     + xv[pi].z*wv.z + xv[pi].w*wv.w;
                }
            }
            __syncthreads();
        }

        // exact gelu -> io (overwrite x tile; all reads done), re-init acc, stage G2 chunk0
#pragma unroll
        for (int jj = 0; jj < 6; ++jj) {
            int j = jg + 32*jj;
#pragma unroll
            for (int pi = 0; pi < 4; ++pi) {
                float g = acc[pi][jj];
                io[(pg + 8*pi)*200 + j] =
                    0.5f * g * (1.f + erff(g * 0.70710678118654752f));
                acc[pi][jj] = binit[jj];
            }
        }
#pragma unroll
        for (int i = 0; i < 3; ++i) {
            int lin = t + 256*i;
            int j = lin >> 2, q2 = lin & 3;
            wch4[q2*192 + j] = W24[j*48 + q2];
        }
        __syncthreads();

        // GEMM2: 12 chunks of K=16 over j
        for (int ck = 0; ck < 12; ++ck) {
            int cb = ck & 1;
            if (ck < 11) {
                int nb = cb ^ 1;
#pragma unroll
                for (int i = 0; i < 3; ++i) {
                    int lin = t + 256*i;
                    int j = lin >> 2, q2 = lin & 3;
                    wch4[nb*768 + q2*192 + j] = W24[j*48 + (ck+1)*4 + q2];
                }
            }
#pragma unroll
            for (int q2 = 0; q2 < 4; ++q2) {
                float4 hv[4];
#pragma unroll
                for (int pi = 0; pi < 4; ++pi)
                    hv[pi] = io4[(pg + 8*pi)*50 + ck*4 + q2];
#pragma unroll
                for (int jj = 0; jj < 6; ++jj) {
                    float4 wv = wch4[cb*768 + q2*192 + jg + 32*jj];
#pragma unroll
                    for (int pi = 0; pi < 4; ++pi)
                        acc[pi][jj] += hv[pi].x*wv.x + hv[pi].y*wv.y
                                     + hv[pi].z*wv.z + hv[pi].w*wv.w;
                }
            }
            __syncthreads();
        }

        // result -> io (residual added at store from global, L2-hot)
#pragma unroll
        for (int jj = 0; jj < 6; ++jj) {
            int j = jg + 32*jj;
#pragma unroll
            for (int pi = 0; pi < 4; ++pi)
                io[(pg + 8*pi)*200 + j] = acc[pi][jj];
        }
        __syncthreads();
        float4* og4 = (float4*)(out + base);
#pragma unroll
        for (int i = 0; i < 6; ++i) {
            int lin = t + 256*i;
            float4 r  = io4[(lin/48)*50 + (lin%48)];
            float4 xr = xg4[lin];
            r.x += xr.x; r.y += xr.y; r.z += xr.z; r.w += xr.w;
            og4[lin] = r;
        }
        __syncthreads();
    }
}

// ---------------- launch ----------------
extern "C" void kernel_launch(void* const* d_in, const int* in_sizes, int n_in,
                              void* d_out, int out_size, void* d_ws, size_t ws_size,
                              hipStream_t stream) {
    const float* x     = (const float*)d_in[0];
    const float* qkv_w = (const float*)d_in[1];
    const float* qkv_b = (const float*)d_in[2];
    const float* o1_w  = (const float*)d_in[3];
    const float* o1_b  = (const float*)d_in[4];
    const float* o2_w  = (const float*)d_in[5];
    const float* o2_b  = (const float*)d_in[6];
    const float* klnw  = (const float*)d_in[7];
    const float* klnb  = (const float*)d_in[8];
    const float* vlnw  = (const float*)d_in[9];
    const float* vlnb  = (const float*)d_in[10];
    float* out = (float*)d_out;
    float* ws  = (float*)d_ws;

    if (ws_size < (size_t)395136 * sizeof(float)) return;

    float* wkv = ws;               // 73728
    float* bkv = ws + 73728;       // 384
    float* kvg = ws + 74112;       // 24576
    float* Pt  = ws + 98688;       // 147456
    float* c0  = ws + 246144;      // 768
    float* M1t = ws + 246912;      // 147456
    float* d1  = ws + 394368;      // 768

    hipMemsetAsync(kvg, 0, 24576 * sizeof(float), stream);
    k0_pack<<<289, 256, 0, stream>>>(qkv_w, qkv_b, wkv, bkv);
    k1_kv<<<dim3(256, 4), 256, 0, stream>>>(x, wkv, bkv, klnw, klnb, vlnw, vlnb, kvg);
    k2a<<<dim3(145, 4), 256, 0, stream>>>(qkv_w, qkv_b, kvg, Pt, c0);
    k2b<<<dim3(145, 4), 256, 0, stream>>>(o1_w, o1_b, Pt, c0, M1t, d1);
    k3_out<<<dim3(256, 4), 256, 0, stream>>>(x, M1t, d1, o2_w, o2_b, out);
}

// Round 2
// 627.442 us; speedup vs baseline: 3.3090x; 3.3090x over previous
//
#include <hip/hip_runtime.h>
#include <math.h>

typedef __attribute__((ext_vector_type(8)))  __bf16 bf16x8;
typedef __attribute__((ext_vector_type(16))) float  f32x16;
typedef __attribute__((ext_vector_type(4)))  float  f32x4;
typedef __attribute__((ext_vector_type(4)))  int    i32x4;
typedef __attribute__((ext_vector_type(4)))  unsigned u32x4;

union FR { bf16x8 v; u32x4 q; unsigned u[4]; };

__device__ inline f32x16 MF(bf16x8 a, bf16x8 b, f32x16 c) {
    return __builtin_amdgcn_mfma_f32_32x32x16_bf16(a, b, c, 0, 0, 0);
}
__device__ inline unsigned pk(float a, float b) {
    unsigned ua = (__builtin_bit_cast(unsigned, a) + 0x8000u) >> 16;
    unsigned ub = (__builtin_bit_cast(unsigned, b) + 0x8000u) >> 16;
    return ua | (ub << 16);
}
__device__ inline unsigned short bfr(float a) {
    return (unsigned short)((__builtin_bit_cast(unsigned, a) + 0x8000u) >> 16);
}
__device__ inline float ubf(unsigned short s) {
    return __builtin_bit_cast(float, (unsigned)s << 16);
}
// exact-erf GELU via Abramowitz-Stegun 7.1.26 (|err| < 1.5e-7)
__device__ inline float gelu_f(float g) {
    float z  = g * 0.70710678118654752f;
    float az = fabsf(z);
    float t  = 1.0f / (1.0f + 0.3275911f * az);
    float poly = t*(0.254829592f + t*(-0.284496736f + t*(1.421413741f +
                 t*(-1.453152027f + t*1.061405429f))));
    float er = 1.0f - poly * __expf(-az * az);
    er = (z < 0.f) ? -er : er;
    return 0.5f * g * (1.0f + er);
}

// ---------------- k0: pack Wkv + o2w into MFMA B-frag order, pack bkv ---------
// wkvpk: [kt12][nt12][l64][q4] uints ; frag elem = W[nt*32+(l&31)][kt*16+(l>>5)*8+2q..+1]
__global__ void k0_pack(const float* __restrict__ qkv_w, const float* __restrict__ qkv_b,
                        const float* __restrict__ o2w,
                        unsigned* __restrict__ wkvpk, unsigned* __restrict__ o2pk,
                        float* __restrict__ bkv)
{
    int idx = blockIdx.x * 256 + threadIdx.x;
    if (idx < 36864) {
        int kt = idx / 3072, r = idx % 3072, nt = r / 256, r3 = r % 256;
        int l = r3 >> 2, q = r3 & 3;
        int c  = kt * 16 + (l >> 5) * 8 + q * 2;
        int rp = nt * 32 + (l & 31);
        int row = (rp >> 6) * 96 + 32 + (rp & 63);       // k rows 32..63, v rows 64..95
        wkvpk[idx] = pk(qkv_w[row * 192 + c], qkv_w[row * 192 + c + 1]);
    } else if (idx < 55296) {
        int i2 = idx - 36864;
        int kt = i2 / 1536, r = i2 % 1536, jt = r / 256, r3 = r % 256;
        int l = r3 >> 2, q = r3 & 3;
        int jj = kt * 16 + (l >> 5) * 8 + q * 2;
        int j  = jt * 32 + (l & 31);
        o2pk[i2] = pk(o2w[j * 192 + jj], o2w[j * 192 + jj + 1]);
    } else if (idx < 55680) {
        int rp = idx - 55296;
        bkv[rp] = qkv_b[(rp >> 6) * 96 + 32 + (rp & 63)];
    }
}

// ---------------- k1a: k/v projection via MFMA, raw bf16 out (C-layout packed) --
// grid 2048 x 256. wave = 32-px strip-pair; no LDS, no barriers.
__global__ __launch_bounds__(256, 2)
void k1a(const float* __restrict__ x, const u32x4* __restrict__ Wpk,
         const float* __restrict__ bkv, u32x4* __restrict__ kvraw)
{
    const int tid = threadIdx.x;
    const int wid = tid >> 6, lane = tid & 63;
    const int col = lane & 31, lh = lane >> 5;
    const int w = blockIdx.x * 4 + wid;
    const int b = w >> 11, sp = w & 2047;

    const float* xr = x + ((long)(b * 65536 + sp * 32 + col)) * 192 + lh * 8;
    FR afr[12];
#pragma unroll
    for (int kt = 0; kt < 12; ++kt) {
        f32x4 a0 = *(const f32x4*)(xr + kt * 16);
        f32x4 a1 = *(const f32x4*)(xr + kt * 16 + 4);
        afr[kt].u[0] = pk(a0.x, a0.y); afr[kt].u[1] = pk(a0.z, a0.w);
        afr[kt].u[2] = pk(a1.x, a1.y); afr[kt].u[3] = pk(a1.z, a1.w);
    }
    float biasv[12];
#pragma unroll
    for (int nt = 0; nt < 12; ++nt) biasv[nt] = bkv[nt * 32 + col];

#pragma unroll
    for (int half = 0; half < 2; ++half) {
        f32x16 acc[6];
#pragma unroll
        for (int n = 0; n < 6; ++n) acc[n] = (f32x16)(biasv[half * 6 + n]);
#pragma unroll
        for (int kt = 0; kt < 12; ++kt) {
            bf16x8 av = afr[kt].v;
#pragma unroll
            for (int n = 0; n < 6; ++n) {
                FR bv; bv.q = Wpk[(kt * 12 + half * 6 + n) * 64 + lane];
                acc[n] = MF(av, bv.v, acc[n]);
            }
        }
#pragma unroll
        for (int n = 0; n < 6; ++n) {
            int nt = half * 6 + n;
            u32x4 lo, hi;
            lo.x = pk(acc[n][0],  acc[n][1]);  lo.y = pk(acc[n][2],  acc[n][3]);
            lo.z = pk(acc[n][4],  acc[n][5]);  lo.w = pk(acc[n][6],  acc[n][7]);
            hi.x = pk(acc[n][8],  acc[n][9]);  hi.y = pk(acc[n][10], acc[n][11]);
            hi.z = pk(acc[n][12], acc[n][13]); hi.w = pk(acc[n][14], acc[n][15]);
            long base = ((long)((b * 2048 + sp) * 12 + nt)) * 128 + lane * 2;
            kvraw[base] = lo; kvraw[base + 1] = hi;
        }
    }
}

// ---------------- k1b: LN(k),LN(v) + kv = k^T v via MFMA -----------------------
// grid (64 splits, 6 heads, 4 batch) x 256
__global__ __launch_bounds__(256, 2)
void k1b(const u32x4* __restrict__ kvraw,
         const float* __restrict__ klnw, const float* __restrict__ klnb,
         const float* __restrict__ vlnw, const float* __restrict__ vlnb,
         float* __restrict__ kvg)
{
    __shared__ __align__(16) unsigned short kvT[64 * 40];  // [ch 0..63][px pad40]
    __shared__ float stats[4][64][2];
    __shared__ float smean[64], sinv[64];
    __shared__ float lnw_s[64], lnb_s[64];

    const int t = threadIdx.x;
    const int split = blockIdx.x, h = blockIdx.y, b = blockIdx.z;

    if (t < 32)      { lnw_s[t] = klnw[h * 32 + t];      lnb_s[t] = klnb[h * 32 + t]; }
    else if (t < 64) { lnw_s[t] = vlnw[h * 32 + t - 32]; lnb_s[t] = vlnb[h * 32 + t - 32]; }

    const int lane = t & 63;
    const int col = lane & 31, lh = lane >> 5;
    // load mapping: thread covers (nt, l, r-half)
    const int nt  = 2 * h + (t >> 7);
    const int l   = (t & 127) >> 1;
    const int rh  = (t & 1) * 8;
    const int chw = (t >> 7) * 32 + (l & 31);
    const int p0  = 4 * (l >> 5) + rh * 2;   // rh=0 -> 0, rh=8 -> 16
    const int c64 = t & 63, pp = c64 & 31, kvh = c64 >> 5, qq = t >> 6;

    f32x16 kvacc = (f32x16)(0.0f);

    for (int c = 0; c < 32; ++c) {
        int sp = split * 32 + c;
        __syncthreads();   // previous chunk's MFMA reads done
        u32x4 d = kvraw[((long)((b * 2048 + sp) * 12 + nt)) * 128 + l * 2 + (t & 1)];
        *(uint2*)&kvT[chw * 40 + p0]     = make_uint2(d.x, d.y);
        *(uint2*)&kvT[chw * 40 + p0 + 8] = make_uint2(d.z, d.w);
        __syncthreads();
        // stats over 8 channels each
        float vals[8]; float s = 0.f, s2 = 0.f;
#pragma unroll
        for (int i = 0; i < 8; ++i) {
            int ch = kvh * 32 + qq * 8 + i;
            float f = ubf(kvT[ch * 40 + pp]);
            vals[i] = f; s += f; s2 += f * f;
        }
        stats[qq][c64][0] = s; stats[qq][c64][1] = s2;
        __syncthreads();
        if (t < 64) {
            float ss = 0.f, ss2 = 0.f;
#pragma unroll
            for (int q = 0; q < 4; ++q) { ss += stats[q][t][0]; ss2 += stats[q][t][1]; }
            float m = ss * (1.f / 32.f);
            float var = fmaxf((ss2 - 32.f * m * m) * (1.f / 31.f), 0.f);
            smean[t] = m; sinv[t] = 1.f / (sqrtf(var) + 1e-5f);
        }
        __syncthreads();
        float m = smean[c64], inv = sinv[c64];
#pragma unroll
        for (int i = 0; i < 8; ++i) {
            int ch = kvh * 32 + qq * 8 + i;
            float f = lnw_s[ch] * ((vals[i] - m) * inv) + lnb_s[ch];
            kvT[ch * 40 + pp] = bfr(f);
        }
        __syncthreads();
        if (t < 64) {
#pragma unroll
            for (int kt2 = 0; kt2 < 2; ++kt2) {
                i32x4 ar = *(const i32x4*)&kvT[col * 40 + kt2 * 16 + lh * 8];
                i32x4 br = *(const i32x4*)&kvT[(32 + col) * 40 + kt2 * 16 + lh * 8];
                kvacc = MF(__builtin_bit_cast(bf16x8, ar),
                           __builtin_bit_cast(bf16x8, br), kvacc);
            }
        }
    }
    if (t < 64) {
#pragma unroll
        for (int r = 0; r < 16; ++r) {
            int dd = (r & 3) + 4 * lh + 8 * (r >> 2);
            atomicAdd(&kvg[((b * 6 + h) * 32 + dd) * 32 + col],
                      kvacc[r] * (1.f / 65536.f));
        }
    }
}

// ---------------- k2a: Pt[b][cp][c], c0[b][cp] (fp32, exact q path) ------------
__global__ void k2a(const float* __restrict__ qkv_w, const float* __restrict__ qkv_b,
                    const float* __restrict__ kvg,
                    float* __restrict__ Pt, float* __restrict__ c0)
{
    int b = blockIdx.y;
    const float* kvb = kvg + (long)b * 6144;
    if (blockIdx.x < 144) {
        int idx = blockIdx.x * 256 + threadIdx.x;
        int c = idx % 192, cp = idx / 192;
        int h = cp >> 5, e = cp & 31;
        float s = 0.f;
#pragma unroll 8
        for (int d = 0; d < 32; ++d)
            s += qkv_w[(h * 96 + d) * 192 + c] * kvb[(h * 32 + d) * 32 + e];
        Pt[(long)b * 36864 + cp * 192 + c] = s;
    } else if (threadIdx.x < 192) {
        int cp = threadIdx.x, h = cp >> 5, e = cp & 31;
        float s = 0.f;
#pragma unroll 8
        for (int d = 0; d < 32; ++d)
            s += qkv_b[h * 96 + d] * kvb[(h * 32 + d) * 32 + e];
        c0[b * 192 + cp] = s;
    }
}

// ---------------- k2b: M1t[b][j][c], d1[b][j] ----------------------------------
__global__ void k2b(const float* __restrict__ o1w, const float* __restrict__ o1b,
                    const float* __restrict__ Pt, const float* __restrict__ c0,
                    float* __restrict__ M1t, float* __restrict__ d1)
{
    int b = blockIdx.y;
    if (blockIdx.x < 144) {
        int idx = blockIdx.x * 256 + threadIdx.x;
        int c = idx % 192, j = idx / 192;
        float s = o1w[j * 192 + c];
        const float* pb = Pt + (long)b * 36864;
        const float* wr = o1w + j * 192;
#pragma unroll 8
        for (int cp = 0; cp < 192; ++cp)
            s += pb[cp * 192 + c] * wr[cp];
        M1t[(long)b * 36864 + j * 192 + c] = s;
    } else if (threadIdx.x < 192) {
        int j = threadIdx.x;
        float s = o1b[j];
        const float* wr = o1w + j * 192;
#pragma unroll 8
        for (int cp = 0; cp < 192; ++cp)
            s += c0[b * 192 + cp] * wr[cp];
        d1[b * 192 + j] = s;
    }
}

// ---------------- k2c: pack M1t -> bf16 B-frag order ---------------------------
__global__ void k2c(const float* __restrict__ M1t, unsigned* __restrict__ M1pk)
{
    int idx = blockIdx.x * 256 + threadIdx.x;
    if (idx < 73728) {
        int b = idx / 18432, r = idx % 18432;
        int kt = r / 1536, r2 = r % 1536, jt = r2 / 256, r3 = r2 % 256;
        int l = r3 >> 2, q = r3 & 3;
        int c = kt * 16 + (l >> 5) * 8 + q * 2;
        int j = jt * 32 + (l & 31);
        const float* src = M1t + (long)b * 36864 + j * 192 + c;
        M1pk[idx] = pk(src[0], src[1]);
    }
}

// ---------------- k3: out = gelu(x@M1^T)@o2^T + o2b + x via 2x MFMA ------------
// grid 2048 x 256; wave = 32-px strip; LDS only for C->A layout transform of h.
__global__ __launch_bounds__(256, 2)
void k3(const float* __restrict__ x, const u32x4* __restrict__ M1bf,
        const float* __restrict__ d1, const u32x4* __restrict__ o2bf,
        const float* __restrict__ o2b, float* __restrict__ out)
{
    __shared__ __align__(16) unsigned short hbuf[4][32 * 200];
    const int tid = threadIdx.x;
    const int wid = tid >> 6, lane = tid & 63;
    const int col = lane & 31, lh = lane >> 5;
    const int w = blockIdx.x * 4 + wid;
    const int b = w >> 11, sp = w & 2047;

    const float* xrow = x + ((long)(b * 65536 + sp * 32)) * 192;
    const float* xr = xrow + col * 192 + lh * 8;
    FR afr[12];
#pragma unroll
    for (int kt = 0; kt < 12; ++kt) {
        f32x4 a0 = *(const f32x4*)(xr + kt * 16);
        f32x4 a1 = *(const f32x4*)(xr + kt * 16 + 4);
        afr[kt].u[0] = pk(a0.x, a0.y); afr[kt].u[1] = pk(a0.z, a0.w);
        afr[kt].u[2] = pk(a1.x, a1.y); afr[kt].u[3] = pk(a1.z, a1.w);
    }
    float d1v[6], o2bv[6];
#pragma unroll
    for (int jt = 0; jt < 6; ++jt) {
        d1v[jt]  = d1[b * 192 + jt * 32 + col];
        o2bv[jt] = o2b[jt * 32 + col];
    }

    // GEMM1: g = x @ M1^T + d1
    f32x16 acc[6];
#pragma unroll
    for (int jt = 0; jt < 6; ++jt) acc[jt] = (f32x16)(d1v[jt]);
    const u32x4* W1 = M1bf + b * 4608;
#pragma unroll
    for (int kt = 0; kt < 12; ++kt) {
        bf16x8 av = afr[kt].v;
#pragma unroll
        for (int jt = 0; jt < 6; ++jt) {
            FR bv; bv.q = W1[(kt * 6 + jt) * 64 + lane];
            acc[jt] = MF(av, bv.v, acc[jt]);
        }
    }
    // GELU -> LDS (C-layout scatter; row stride 200 shorts => conflict-free)
    unsigned short* hb = hbuf[wid];
#pragma unroll
    for (int jt = 0; jt < 6; ++jt)
#pragma unroll
        for (int r = 0; r < 16; ++r) {
            int p = (r & 3) + 4 * lh + 8 * (r >> 2);
            hb[p * 200 + jt * 32 + col] = bfr(gelu_f(acc[jt][r]));
        }
    __syncthreads();
    // h as A-frags
    i32x4 hfr[12];
#pragma unroll
    for (int kt = 0; kt < 12; ++kt)
        hfr[kt] = *(const i32x4*)&hb[col * 200 + kt * 16 + lh * 8];
    // GEMM2: o = h @ o2^T
    f32x16 acc2[6];
#pragma unroll
    for (int jt = 0; jt < 6; ++jt) acc2[jt] = (f32x16)(0.0f);
#pragma unroll
    for (int kt = 0; kt < 12; ++kt) {
        bf16x8 av = __builtin_bit_cast(bf16x8, hfr[kt]);
#pragma unroll
        for (int jt = 0; jt < 6; ++jt) {
            FR bv; bv.q = o2bf[(kt * 6 + jt) * 64 + lane];
            acc2[jt] = MF(av, bv.v, acc2[jt]);
        }
    }
    // epilogue: + o2b + x (residual, fp32-exact), C-layout stores
    float* orow = out + ((long)(b * 65536 + sp * 32)) * 192;
#pragma unroll
    for (int jt = 0; jt < 6; ++jt) {
        int j = jt * 32 + col;
#pragma unroll
        for (int r = 0; r < 16; ++r) {
            int p = (r & 3) + 4 * lh + 8 * (r >> 2);
            orow[p * 192 + j] = acc2[jt][r] + o2bv[jt] + xrow[p * 192 + j];
        }
    }
}

// ---------------- launch -------------------------------------------------------
extern "C" void kernel_launch(void* const* d_in, const int* in_sizes, int n_in,
                              void* d_out, int out_size, void* d_ws, size_t ws_size,
                              hipStream_t stream) {
    const float* x     = (const float*)d_in[0];
    const float* qkv_w = (const float*)d_in[1];
    const float* qkv_b = (const float*)d_in[2];
    const float* o1_w  = (const float*)d_in[3];
    const float* o1_b  = (const float*)d_in[4];
    const float* o2_w  = (const float*)d_in[5];
    const float* o2_b  = (const float*)d_in[6];
    const float* klnw  = (const float*)d_in[7];
    const float* klnb  = (const float*)d_in[8];
    const float* vlnw  = (const float*)d_in[9];
    const float* vlnb  = (const float*)d_in[10];
    float* out = (float*)d_out;
    float* ws  = (float*)d_ws;

    if (ws_size < (size_t)450432 * sizeof(float)) return;

    unsigned* wkvpk = (unsigned*)(ws);            // 36864 uints
    float*    bkv   = ws + 36864;                 // 384
    float*    kvg   = ws + 37248;                 // 24576
    float*    Pt    = ws + 61824;                 // 147456
    float*    c0    = ws + 209280;                // 768
    float*    M1t   = ws + 210048;                // 147456
    float*    d1    = ws + 357504;                // 768
    unsigned* M1pk  = (unsigned*)(ws + 358272);   // 73728 uints
    unsigned* o2pk  = (unsigned*)(ws + 432000);   // 18432 uints

    hipMemsetAsync(kvg, 0, 24576 * sizeof(float), stream);
    k0_pack<<<218, 256, 0, stream>>>(qkv_w, qkv_b, o2_w, wkvpk, o2pk, bkv);
    // d_out doubles as scratch for raw bf16 k/v (exact size match); k3 overwrites it.
    k1a<<<2048, 256, 0, stream>>>(x, (const u32x4*)wkvpk, bkv, (u32x4*)d_out);
    k1b<<<dim3(64, 6, 4), 256, 0, stream>>>((const u32x4*)d_out,
                                            klnw, klnb, vlnw, vlnb, kvg);
    k2a<<<dim3(145, 4), 256, 0, stream>>>(qkv_w, qkv_b, kvg, Pt, c0);
    k2b<<<dim3(145, 4), 256, 0, stream>>>(o1_w, o1_b, Pt, c0, M1t, d1);
    k2c<<<288, 256, 0, stream>>>(M1t, M1pk);
    k3<<<2048, 256, 0, stream>>>(x, (const u32x4*)M1pk, d1, (const u32x4*)o2pk,
                                 o2_b, out);
}